// Round 6
// baseline (110.274 us; speedup 1.0000x reference)
//
#include <hip/hip_runtime.h>
#include <cstdint>
#include <cstddef>

#define BATCH  8
#define SEQ    4096
#define CHN    256        // channels (OUT)
#define NQ     768        // 3*OUT
#define KTOT   512        // WIN*IN
#define TS     128        // scan chunk length
#define NCHUNK (SEQ/TS)   // 32
#define SROW   4097       // padded rows per batch in Xbf (row 0 = zeros)

typedef __attribute__((ext_vector_type(8))) __bf16    bf16x8;
typedef __attribute__((ext_vector_type(4))) float     f32x4;
typedef __attribute__((ext_vector_type(4))) _Float16  f16x4;
typedef __attribute__((ext_vector_type(2))) _Float16  f16x2;

// ---------------------------------------------------------------------------
// K0a: convert W (fp32 [768][512]) into frag-major bf16 tiles:
//      Wt[(t*4+g)*768 + n][j] = bf16(W[n][t*32 + g*8 + j]),  t<16, g<4, j<8
// ---------------------------------------------------------------------------
__global__ __launch_bounds__(256) void k_convW(const float* __restrict__ W,
                                               __bf16* __restrict__ Wt) {
    int lin = blockIdx.x * 256 + threadIdx.x;   // 0 .. 49151  (= 64*768)
    int n  = lin % NQ;
    int tg = lin / NQ;                          // t*4+g, 0..63
    const float* src = W + (size_t)n * KTOT + tg * 8;
    float4 a = *(const float4*)(src);
    float4 b = *(const float4*)(src + 4);
    bf16x8 h;
    h[0]=(__bf16)a.x; h[1]=(__bf16)a.y; h[2]=(__bf16)a.z; h[3]=(__bf16)a.w;
    h[4]=(__bf16)b.x; h[5]=(__bf16)b.y; h[6]=(__bf16)b.z; h[7]=(__bf16)b.w;
    *(bf16x8*)(Wt + (size_t)lin * 8) = h;
}

// ---------------------------------------------------------------------------
// K0b: convert x (fp32 [8][4096][256]) -> Xbf ([8][4097][256] bf16, row 0 = 0)
// ---------------------------------------------------------------------------
__global__ __launch_bounds__(256) void k_convX(const float* __restrict__ x,
                                               __bf16* __restrict__ Xb) {
    int c = blockIdx.x * 256 + threadIdx.x;     // 0 .. 1048575 (8*4096*256/8)
    if (c < 8 * 32) {                           // zero the 8 pad rows
        int bz = c >> 5, j = c & 31;
        bf16x8 zz = {};
        *(bf16x8*)(Xb + (size_t)bz * SROW * 256 + j * 8) = zz;
    }
    int bi = c >> 17;                           // 131072 chunks per batch
    int r  = c & 131071;
    int s  = r >> 5;
    int j  = r & 31;
    const float* src = x + ((size_t)bi * SEQ + s) * 256 + j * 8;
    float4 a = *(const float4*)(src);
    float4 b = *(const float4*)(src + 4);
    bf16x8 h;
    h[0]=(__bf16)a.x; h[1]=(__bf16)a.y; h[2]=(__bf16)a.z; h[3]=(__bf16)a.w;
    h[4]=(__bf16)b.x; h[5]=(__bf16)b.y; h[6]=(__bf16)b.z; h[7]=(__bf16)b.w;
    *(bf16x8*)(Xb + ((size_t)bi * SROW + 1 + s) * 256 + j * 8) = h;
}

__device__ __forceinline__ float fast_sigmoid(float y) {
    float e = __expf(-y);
    return __builtin_amdgcn_rcpf(1.f + e);
}
__device__ __forceinline__ float fast_tanh(float y) {
    float e = __expf(-2.f * y);
    return __builtin_amdgcn_rcpf(1.f + e) * 2.f - 1.f;
}

// ---------------------------------------------------------------------------
// K1: GEMM (transposed: y^T = W * xw^T) + activations. PURE-STREAM design:
// no input LDS, no barriers, no setprio. Block = 256 thr = 4 waves (one gate,
// block-uniform); wave wid covers n [nb*256+wid*64, +64) x s [s0, s0+64).
// Both operands stream from L2/L1 into registers, 1-t-deep double buffer.
// 3 waves/SIMD from 3 independent blocks hide each other's load stalls.
// Epilogue: per-wave LDS transpose (8 KB, XOR-swizzled) -> 128B-coalesced
// stores. Grid = 3 nb * 8 bi * 64 sb = 1536; X-sharing blocks differ by 512
// (=0 mod 8) -> same XCD under round-robin dispatch.
// ---------------------------------------------------------------------------
__global__ __launch_bounds__(256, 3) void k_gemm(
    const __bf16* __restrict__ Xb, const __bf16* __restrict__ Wt,
    const float* __restrict__ bias,
    _Float16* __restrict__ Zb, _Float16* __restrict__ Fb, _Float16* __restrict__ Ob)
{
    __shared__ char Ep[4][8192];                // per-wave epilogue scratch

    int tid = threadIdx.x;
    int bid = blockIdx.x;
    int nb  = bid >> 9;          // 0..2 : gate
    int bi  = (bid >> 6) & 7;
    int sb  = bid & 63;
    int s0  = sb * 64;
    int wid = tid >> 6;
    int l   = tid & 63;
    int l15 = l & 15, lg = l >> 4;
    int nbase = nb * 256 + wid * 64;

    // W: elem = t*24576 + lg*6144 + (nbase + nt*16 + l15)*8
    const __bf16* wp = Wt + (size_t)lg * 6144 + (nbase + l15) * 8;
    // X: row = bi*SROW + s0 + l15 + st*16 + (t>>3); col = lg*8 + (t&7)*32
    const __bf16* xp = Xb + ((size_t)bi * SROW + s0 + l15) * 256 + lg * 8;

    #define LOADW(dst, t)                                                        \
        { _Pragma("unroll")                                                      \
          for (int nt = 0; nt < 4; ++nt)                                         \
              dst[nt] = *(const bf16x8*)(wp + (size_t)(t) * 24576 + nt * 128); }
    #define LOADX(dst, t)                                                        \
        { _Pragma("unroll")                                                      \
          for (int st = 0; st < 4; ++st)                                         \
              dst[st] = *(const bf16x8*)(xp + (size_t)(st * 16 + ((t) >> 3)) * 256 \
                                            + ((t) & 7) * 32); }

    bf16x8 wf[2][4], xf[2][4];
    LOADW(wf[0], 0);
    LOADX(xf[0], 0);

    f32x4 acc[4][4];
    const f32x4 vzero = {0.f, 0.f, 0.f, 0.f};
    #pragma unroll
    for (int a = 0; a < 4; ++a)
        #pragma unroll
        for (int b = 0; b < 4; ++b)
            acc[a][b] = vzero;

    // ---- K loop: 16 t-steps of K=32; zero barriers, 1-deep prefetch ----
    #pragma unroll
    for (int t = 0; t < 16; ++t) {
        int cur = t & 1, nxt = cur ^ 1;
        if (t < 15) { LOADW(wf[nxt], t + 1); LOADX(xf[nxt], t + 1); }
        #pragma unroll
        for (int nt = 0; nt < 4; ++nt)
            #pragma unroll
            for (int st = 0; st < 4; ++st)
                acc[nt][st] = __builtin_amdgcn_mfma_f32_16x16x32_bf16(
                                  wf[cur][nt], xf[cur][st], acc[nt][st], 0, 0, 0);
    }

    // ---- epilogue: activation -> per-wave LDS transpose -> coalesced store ----
    char* Lw = Ep[wid];
    // Phase A: lane writes f16x4 (4 ch at fixed s) to LDS[s_loc][ch_loc]
    #pragma unroll
    for (int nt = 0; nt < 4; ++nt) {
        float4 bv = *(const float4*)(bias + nbase + nt * 16 + lg * 4);
        #pragma unroll
        for (int st = 0; st < 4; ++st) {
            f16x4 h;
            #pragma unroll
            for (int r = 0; r < 4; ++r) {
                float bvr = (r == 0) ? bv.x : (r == 1) ? bv.y : (r == 2) ? bv.z : bv.w;
                float y = acc[nt][st][r] + bvr;
                float v = (nb == 0) ? fast_tanh(y) : fast_sigmoid(y);
                h[r] = (_Float16)v;
            }
            int byte = ((st * 16 + l15) * 128 + (nt * 16 + lg * 4) * 2)
                       ^ ((l15 & 7) << 4);
            *(f16x4*)(Lw + byte) = h;
        }
    }
    // Phase B: lane reads [s_loc][ (l&15)*4 ], stores 128B-contiguous rows
    _Float16* buf = (nb == 0) ? Zb : (nb == 1) ? Fb : Ob;
    int chb = wid * 64;                          // within-gate channel base
    #pragma unroll
    for (int so = 0; so < 16; ++so) {
        int s_loc = so * 4 + (l >> 4);
        int byte = (s_loc * 128 + (l & 15) * 8) ^ ((s_loc & 7) << 4);
        f16x4 v = *(const f16x4*)(Lw + byte);
        *(f16x4*)(buf + ((size_t)bi * SEQ + s0 + s_loc) * CHN + chb + (l & 15) * 4) = v;
    }
}

// ---------------------------------------------------------------------------
// K2: per-chunk scan summaries; thread handles 2 channels (4B f16x2 loads).
// ---------------------------------------------------------------------------
__global__ __launch_bounds__(128) void k_scan1(const _Float16* __restrict__ Fb,
                                               const _Float16* __restrict__ Zb,
                                               float* __restrict__ Aq,
                                               float* __restrict__ Bq) {
    int bi = blockIdx.x >> 5;
    int ck = blockIdx.x & 31;
    int c2 = threadIdx.x;                       // channel pair 0..127
    size_t base = (((size_t)bi * SEQ + ck * TS) * CHN + c2 * 2) >> 1;
    const f16x2* F2 = (const f16x2*)Fb;
    const f16x2* Z2 = (const f16x2*)Zb;
    float a0 = 1.f, a1 = 1.f, c0 = 0.f, c1 = 0.f;
    #pragma unroll 8
    for (int s = 0; s < TS; ++s) {
        f16x2 f = F2[base + (size_t)s * (CHN / 2)];
        f16x2 z = Z2[base + (size_t)s * (CHN / 2)];
        float f0 = (float)f[0], f1 = (float)f[1];
        c0 = f0 * c0 + (1.f - f0) * (float)z[0];
        c1 = f1 * c1 + (1.f - f1) * (float)z[1];
        a0 *= f0; a1 *= f1;
    }
    int o = blockIdx.x * CHN + c2 * 2;
    *(float2*)(Aq + o) = make_float2(a0, a1);
    *(float2*)(Bq + o) = make_float2(c0, c1);
}

// ---------------------------------------------------------------------------
// K3: sequential carry across chunks. 8 blocks x 256 threads, 32 steps.
// ---------------------------------------------------------------------------
__global__ __launch_bounds__(256) void k_scan2(const float* __restrict__ Aq,
                                               const float* __restrict__ Bq,
                                               float* __restrict__ Cq) {
    int bi = blockIdx.x;
    int ch = threadIdx.x;
    float c = 0.f;
    #pragma unroll
    for (int ck = 0; ck < NCHUNK; ++ck) {
        int o = (bi * NCHUNK + ck) * CHN + ch;
        Cq[o] = c;
        c = Aq[o] * c + Bq[o];
    }
}

// ---------------------------------------------------------------------------
// K4: final pass — redo local scan seeded with carry, out = sigmoid(o) * c.
// ---------------------------------------------------------------------------
__global__ __launch_bounds__(128) void k_scan3(const _Float16* __restrict__ Fb,
                                               const _Float16* __restrict__ Zb,
                                               const _Float16* __restrict__ Ob,
                                               const float* __restrict__ Cq,
                                               float* __restrict__ out) {
    int bi = blockIdx.x >> 5;
    int ck = blockIdx.x & 31;
    int c2 = threadIdx.x;
    float2 c = *(const float2*)(Cq + blockIdx.x * CHN + c2 * 2);
    size_t base = (((size_t)bi * SEQ + ck * TS) * CHN + c2 * 2) >> 1;
    const f16x2* F2 = (const f16x2*)Fb;
    const f16x2* Z2 = (const f16x2*)Zb;
    const f16x2* O2 = (const f16x2*)Ob;
    float* outp = out + (((size_t)bi * SEQ + ck * TS) * CHN + c2 * 2);
    #pragma unroll 4
    for (int s = 0; s < TS; ++s) {
        f16x2 f  = F2[base + (size_t)s * (CHN / 2)];
        f16x2 z  = Z2[base + (size_t)s * (CHN / 2)];
        f16x2 so = O2[base + (size_t)s * (CHN / 2)];
        float f0 = (float)f[0], f1 = (float)f[1];
        c.x = f0 * c.x + (1.f - f0) * (float)z[0];
        c.y = f1 * c.y + (1.f - f1) * (float)z[1];
        *(float2*)(outp + (size_t)s * CHN) = make_float2((float)so[0] * c.x,
                                                         (float)so[1] * c.y);
    }
}

// ---------------------------------------------------------------------------
extern "C" void kernel_launch(void* const* d_in, const int* in_sizes, int n_in,
                              void* d_out, int out_size, void* d_ws, size_t ws_size,
                              hipStream_t stream)
{
    const float* x = (const float*)d_in[0];   // (8,4096,256) fp32
    const float* W = (const float*)d_in[1];   // (768,512)    fp32
    const float* b = (const float*)d_in[2];   // (768,)       fp32
    float* out = (float*)d_out;               // (8,4096,256) fp32

    char* ws = (char*)d_ws;
    const size_t MB = 1024 * 1024;
    _Float16* Zb = (_Float16*)(ws +  0 * MB);   // 16 MB
    _Float16* Fb = (_Float16*)(ws + 16 * MB);   // 16 MB
    _Float16* Ob = (_Float16*)(ws + 32 * MB);   // 16 MB
    __bf16*   Wt = (__bf16*)  (ws + 48 * MB);   // 768 KB
    float*    Aq = (float*)   (ws + 49 * MB);   // 256 KB
    float*    Bq = (float*)   (ws + 50 * MB);   // 256 KB
    float*    Cq = (float*)   (ws + 51 * MB);   // 256 KB
    __bf16*   Xb = (__bf16*)  (ws + 52 * MB);   // 8*4097*256*2 B = 16.02 MB

    k_convW<<<dim3(192),            dim3(256), 0, stream>>>(W, Wt);
    k_convX<<<dim3(4096),           dim3(256), 0, stream>>>(x, Xb);
    k_gemm <<<dim3(1536),           dim3(256), 0, stream>>>(Xb, Wt, b, Zb, Fb, Ob);
    k_scan1<<<dim3(BATCH * NCHUNK), dim3(128), 0, stream>>>(Fb, Zb, Aq, Bq);
    k_scan2<<<dim3(BATCH),          dim3(256), 0, stream>>>(Aq, Bq, Cq);
    k_scan3<<<dim3(BATCH * NCHUNK), dim3(128), 0, stream>>>(Fb, Zb, Ob, Cq, out);
}

// Round 7
// 83.960 us; speedup vs baseline: 1.3134x; 1.3134x over previous
//
#include <hip/hip_runtime.h>
#include <cstdint>
#include <cstddef>

#define BATCH  8
#define SEQ    4096
#define CHN    256        // channels (OUT)
#define NQ     768        // 3*OUT
#define KTOT   512        // WIN*IN
#define TS     128        // scan chunk length
#define NCHUNK (SEQ/TS)   // 32
#define SROW   4097       // padded rows per batch in Xbf (row 0 = zeros)

#define WPL    4128       // W plane pitch in LDS (4096 + 32 pad)
#define WST    (4*WPL)    // 16512 B per W buffer
#define XOFF   (2*WST)    // 33024 : X buffers start
#define XST    8448       // 132 rows * 64 B per X buffer
#define LDSZ   (XOFF + 2*XST)   // 49920 B

typedef __attribute__((ext_vector_type(8))) __bf16    bf16x8;
typedef __attribute__((ext_vector_type(4))) float     f32x4;
typedef __attribute__((ext_vector_type(4))) _Float16  f16x4;
typedef __attribute__((ext_vector_type(2))) _Float16  f16x2;

// ---------------------------------------------------------------------------
// K0a: W (fp32 [768][512]) -> frag-major bf16 tiles:
//      Wt[(t*4+g)*768 + n][j] = bf16(W[n][t*32 + g*8 + j]),  t<16, g<4, j<8
// ---------------------------------------------------------------------------
__global__ __launch_bounds__(256) void k_convW(const float* __restrict__ W,
                                               __bf16* __restrict__ Wt) {
    int lin = blockIdx.x * 256 + threadIdx.x;   // 0 .. 49151
    int n  = lin % NQ;
    int tg = lin / NQ;
    const float* src = W + (size_t)n * KTOT + tg * 8;
    float4 a = *(const float4*)(src);
    float4 b = *(const float4*)(src + 4);
    bf16x8 h;
    h[0]=(__bf16)a.x; h[1]=(__bf16)a.y; h[2]=(__bf16)a.z; h[3]=(__bf16)a.w;
    h[4]=(__bf16)b.x; h[5]=(__bf16)b.y; h[6]=(__bf16)b.z; h[7]=(__bf16)b.w;
    *(bf16x8*)(Wt + (size_t)lin * 8) = h;
}

// ---------------------------------------------------------------------------
// K0b: x (fp32 [8][4096][256]) -> Xbf ([8][4097][256] bf16, row 0 = zeros)
// ---------------------------------------------------------------------------
__global__ __launch_bounds__(256) void k_convX(const float* __restrict__ x,
                                               __bf16* __restrict__ Xb) {
    int c = blockIdx.x * 256 + threadIdx.x;
    if (c < 8 * 32) {
        int bz = c >> 5, j = c & 31;
        bf16x8 zz = {};
        *(bf16x8*)(Xb + (size_t)bz * SROW * 256 + j * 8) = zz;
    }
    int bi = c >> 17;
    int r  = c & 131071;
    int s  = r >> 5;
    int j  = r & 31;
    const float* src = x + ((size_t)bi * SEQ + s) * 256 + j * 8;
    float4 a = *(const float4*)(src);
    float4 b = *(const float4*)(src + 4);
    bf16x8 h;
    h[0]=(__bf16)a.x; h[1]=(__bf16)a.y; h[2]=(__bf16)a.z; h[3]=(__bf16)a.w;
    h[4]=(__bf16)b.x; h[5]=(__bf16)b.y; h[6]=(__bf16)b.z; h[7]=(__bf16)b.w;
    *(bf16x8*)(Xb + ((size_t)bi * SROW + 1 + s) * 256 + j * 8) = h;
}

__device__ __forceinline__ float fast_sigmoid(float y) {
    float e = __expf(-y);
    return __builtin_amdgcn_rcpf(1.f + e);
}
__device__ __forceinline__ float fast_tanh(float y) {
    float e = __expf(-2.f * y);
    return __builtin_amdgcn_rcpf(1.f + e) * 2.f - 1.f;
}

// ---------------------------------------------------------------------------
// K1: GEMM (y^T = W * xw^T) + activations.  m201-lite structure:
//  - block 256 thr = 4 waves; block tile 128s x 256n (ONE gate, uniform);
//    wave wid: n in [64*wid, +64), full 128 s  ->  acc = 8st x 4nt frags.
//  - per K-step t (K=32): stage W 16KB + X-window 8.26KB via global_load_lds
//    (double-buffered), fragments via ds_read_b128 from LDS; 1 barrier per t.
//  - X LDS tile XOR-slot swizzled (2-way banks); source pre-swizzled (m173).
//  - LDS 49.9KB, ~200 regs -> 2 waves/SIMD -> 2 independent blocks/CU.
//  - epilogue: per-wave LDS transpose (reuses W buffers) -> 128B stores.
// Grid = 3 gates * 8 bi * 32 sc = 768 = 3 exact CU-rounds.
// ---------------------------------------------------------------------------
__global__ __launch_bounds__(256, 2) void k_gemm(
    const __bf16* __restrict__ Xb, const __bf16* __restrict__ Wt,
    const float* __restrict__ bias,
    _Float16* __restrict__ Zb, _Float16* __restrict__ Fb, _Float16* __restrict__ Ob)
{
    __shared__ char Lds[LDSZ];

    int tid = threadIdx.x;
    int bid = blockIdx.x;
    int nsl  = bid % 3;          // gate 0:z 1:f 2:o
    int rest = bid / 3;
    int bi = rest >> 5;
    int sc = rest & 31;
    int s0 = sc * 128;
    int wid = tid >> 6;          // 0..3 : n-group [64*wid, +64) within gate
    int l   = tid & 63;
    int l15 = l & 15, lg = l >> 4;

    // ---- staging: per t, W planes g=0..3 (4KB each) + X rows s0..s0+128 ----
    // W src: lane-contiguous 1KB per wave per plane.
    // X src: qr = quarter-row index; LDS linear slot qr holds global col16
    //        (qr&3)^((qr>>3)&3)  [pre-swizzled source => swizzled read works]
    #define STAGE(bsel, t)                                                       \
        {                                                                        \
            _Pragma("unroll")                                                    \
            for (int g = 0; g < 4; ++g) {                                        \
                const __bf16* gsrc = Wt +                                        \
                    ((size_t)((t) * 4 + g) * NQ + nsl * 256 + wid * 64 + l) * 8; \
                char* ldst = Lds + (bsel) * WST + g * WPL + wid * 1024;          \
                __builtin_amdgcn_global_load_lds(                                \
                    (const __attribute__((address_space(1))) void*)gsrc,         \
                    (__attribute__((address_space(3))) void*)ldst, 16, 0, 0);    \
            }                                                                    \
            _Pragma("unroll")                                                    \
            for (int ro = 0; ro < 2; ++ro) {                                     \
                int qr   = ro * 256 + tid;                                       \
                int row  = qr >> 2;                                              \
                int c16  = (qr & 3) ^ ((qr >> 3) & 3);                           \
                const __bf16* gsrc = Xb +                                        \
                    ((size_t)bi * SROW + s0 + row) * 256 + ((t) & 7) * 32 + c16 * 8; \
                char* ldst = Lds + XOFF + (bsel) * XST + (ro * 256 + wid * 64) * 16; \
                __builtin_amdgcn_global_load_lds(                                \
                    (const __attribute__((address_space(1))) void*)gsrc,         \
                    (__attribute__((address_space(3))) void*)ldst, 16, 0, 0);    \
            }                                                                    \
            if (tid < 4) {                                                       \
                const __bf16* gsrc = Xb +                                        \
                    ((size_t)bi * SROW + s0 + 128) * 256 + ((t) & 7) * 32 + tid * 8; \
                char* ldst = Lds + XOFF + (bsel) * XST + 512 * 16;               \
                __builtin_amdgcn_global_load_lds(                                \
                    (const __attribute__((address_space(1))) void*)gsrc,         \
                    (__attribute__((address_space(3))) void*)ldst, 16, 0, 0);    \
            }                                                                    \
        }

    STAGE(0, 0);

    f32x4 acc[4][8];
    const f32x4 vzero = {0.f, 0.f, 0.f, 0.f};
    #pragma unroll
    for (int a = 0; a < 4; ++a)
        #pragma unroll
        for (int b = 0; b < 8; ++b)
            acc[a][b] = vzero;

    __syncthreads();   // W[0], X[0] staged

    // ---- K loop: 16 t-steps of K=32, double-buffered, 1 barrier per t ----
    #pragma unroll
    for (int t = 0; t < 16; ++t) {
        if (t < 15) STAGE((t + 1) & 1, t + 1);

        int kh = t >> 3;             // 0: x[s-1] rows, 1: x[s] rows
        const char* Xl = Lds + XOFF + (t & 1) * XST;
        bf16x8 xf[8];
        #pragma unroll
        for (int st = 0; st < 8; ++st) {
            int row  = st * 16 + l15 + kh;
            int byte = (row * 64 + lg * 16) ^ (((row >> 1) & 3) << 4);
            xf[st] = *(const bf16x8*)(Xl + byte);
        }
        const char* Wl = Lds + (t & 1) * WST;
        bf16x8 wf[4];
        #pragma unroll
        for (int nt = 0; nt < 4; ++nt)
            wf[nt] = *(const bf16x8*)(Wl + lg * WPL + (wid * 64 + nt * 16 + l15) * 16);

        __builtin_amdgcn_s_setprio(1);
        #pragma unroll
        for (int nt = 0; nt < 4; ++nt)
            #pragma unroll
            for (int st = 0; st < 8; ++st)
                acc[nt][st] = __builtin_amdgcn_mfma_f32_16x16x32_bf16(
                                  wf[nt], xf[st], acc[nt][st], 0, 0, 0);
        __builtin_amdgcn_s_setprio(0);

        if (t < 15) __syncthreads();
    }

    __syncthreads();   // all waves done reading staging LDS -> safe to reuse

    // ---- epilogue: activation -> per-wave LDS transpose -> coalesced store ----
    _Float16* buf = (nsl == 0) ? Zb : (nsl == 1) ? Fb : Ob;
    char* Sw = Lds + wid * 8192;     // 8 KB per-wave scratch (reuses W region)
    float4 bv[4];
    #pragma unroll
    for (int nt = 0; nt < 4; ++nt)
        bv[nt] = *(const float4*)(bias + nsl * 256 + wid * 64 + nt * 16 + lg * 4);

    #pragma unroll
    for (int h = 0; h < 2; ++h) {
        // Phase A: lane writes f16x4 (4 ch at fixed s) into swizzled scratch
        #pragma unroll
        for (int nt = 0; nt < 4; ++nt) {
            #pragma unroll
            for (int st4 = 0; st4 < 4; ++st4) {
                int st = h * 4 + st4;
                f16x4 hv;
                #pragma unroll
                for (int r = 0; r < 4; ++r) {
                    float bvr = (r == 0) ? bv[nt].x : (r == 1) ? bv[nt].y
                              : (r == 2) ? bv[nt].z : bv[nt].w;
                    float y = acc[nt][st][r] + bvr;
                    float v = (nsl == 0) ? fast_tanh(y) : fast_sigmoid(y);
                    hv[r] = (_Float16)v;
                }
                int byte = ((st4 * 16 + l15) * 128 + (nt * 16 + lg * 4) * 2)
                           ^ ((l15 & 7) << 4);
                *(f16x4*)(Sw + byte) = hv;
            }
        }
        // Phase B: read transposed, store 128B-contiguous per 16 lanes
        #pragma unroll
        for (int so = 0; so < 16; ++so) {
            int s_loc = so * 4 + lg;
            int byte  = (s_loc * 128 + l15 * 8) ^ ((s_loc & 7) << 4);
            f16x4 v = *(const f16x4*)(Sw + byte);
            *(f16x4*)(buf + ((size_t)bi * SEQ + s0 + h * 64 + s_loc) * CHN
                          + wid * 64 + l15 * 4) = v;
        }
    }
}

// ---------------------------------------------------------------------------
// K2: per-chunk scan summaries; thread handles 2 channels (4B f16x2 loads).
// ---------------------------------------------------------------------------
__global__ __launch_bounds__(128) void k_scan1(const _Float16* __restrict__ Fb,
                                               const _Float16* __restrict__ Zb,
                                               float* __restrict__ Aq,
                                               float* __restrict__ Bq) {
    int bi = blockIdx.x >> 5;
    int ck = blockIdx.x & 31;
    int c2 = threadIdx.x;
    size_t base = (((size_t)bi * SEQ + ck * TS) * CHN + c2 * 2) >> 1;
    const f16x2* F2 = (const f16x2*)Fb;
    const f16x2* Z2 = (const f16x2*)Zb;
    float a0 = 1.f, a1 = 1.f, c0 = 0.f, c1 = 0.f;
    #pragma unroll 8
    for (int s = 0; s < TS; ++s) {
        f16x2 f = F2[base + (size_t)s * (CHN / 2)];
        f16x2 z = Z2[base + (size_t)s * (CHN / 2)];
        float f0 = (float)f[0], f1 = (float)f[1];
        c0 = f0 * c0 + (1.f - f0) * (float)z[0];
        c1 = f1 * c1 + (1.f - f1) * (float)z[1];
        a0 *= f0; a1 *= f1;
    }
    int o = blockIdx.x * CHN + c2 * 2;
    *(float2*)(Aq + o) = make_float2(a0, a1);
    *(float2*)(Bq + o) = make_float2(c0, c1);
}

// ---------------------------------------------------------------------------
// K3: sequential carry across chunks. 8 blocks x 256 threads, 32 steps.
// ---------------------------------------------------------------------------
__global__ __launch_bounds__(256) void k_scan2(const float* __restrict__ Aq,
                                               const float* __restrict__ Bq,
                                               float* __restrict__ Cq) {
    int bi = blockIdx.x;
    int ch = threadIdx.x;
    float c = 0.f;
    #pragma unroll
    for (int ck = 0; ck < NCHUNK; ++ck) {
        int o = (bi * NCHUNK + ck) * CHN + ch;
        Cq[o] = c;
        c = Aq[o] * c + Bq[o];
    }
}

// ---------------------------------------------------------------------------
// K4: final pass — redo local scan seeded with carry, out = sigmoid(o) * c.
// ---------------------------------------------------------------------------
__global__ __launch_bounds__(128) void k_scan3(const _Float16* __restrict__ Fb,
                                               const _Float16* __restrict__ Zb,
                                               const _Float16* __restrict__ Ob,
                                               const float* __restrict__ Cq,
                                               float* __restrict__ out) {
    int bi = blockIdx.x >> 5;
    int ck = blockIdx.x & 31;
    int c2 = threadIdx.x;
    float2 c = *(const float2*)(Cq + blockIdx.x * CHN + c2 * 2);
    size_t base = (((size_t)bi * SEQ + ck * TS) * CHN + c2 * 2) >> 1;
    const f16x2* F2 = (const f16x2*)Fb;
    const f16x2* Z2 = (const f16x2*)Zb;
    const f16x2* O2 = (const f16x2*)Ob;
    float* outp = out + (((size_t)bi * SEQ + ck * TS) * CHN + c2 * 2);
    #pragma unroll 4
    for (int s = 0; s < TS; ++s) {
        f16x2 f  = F2[base + (size_t)s * (CHN / 2)];
        f16x2 z  = Z2[base + (size_t)s * (CHN / 2)];
        f16x2 so = O2[base + (size_t)s * (CHN / 2)];
        float f0 = (float)f[0], f1 = (float)f[1];
        c.x = f0 * c.x + (1.f - f0) * (float)z[0];
        c.y = f1 * c.y + (1.f - f1) * (float)z[1];
        *(float2*)(outp + (size_t)s * CHN) = make_float2((float)so[0] * c.x,
                                                         (float)so[1] * c.y);
    }
}

// ---------------------------------------------------------------------------
extern "C" void kernel_launch(void* const* d_in, const int* in_sizes, int n_in,
                              void* d_out, int out_size, void* d_ws, size_t ws_size,
                              hipStream_t stream)
{
    const float* x = (const float*)d_in[0];   // (8,4096,256) fp32
    const float* W = (const float*)d_in[1];   // (768,512)    fp32
    const float* b = (const float*)d_in[2];   // (768,)       fp32
    float* out = (float*)d_out;               // (8,4096,256) fp32

    char* ws = (char*)d_ws;
    const size_t MB = 1024 * 1024;
    _Float16* Zb = (_Float16*)(ws +  0 * MB);   // 16 MB
    _Float16* Fb = (_Float16*)(ws + 16 * MB);   // 16 MB
    _Float16* Ob = (_Float16*)(ws + 32 * MB);   // 16 MB
    __bf16*   Wt = (__bf16*)  (ws + 48 * MB);   // 768 KB
    float*    Aq = (float*)   (ws + 49 * MB);   // 256 KB
    float*    Bq = (float*)   (ws + 50 * MB);   // 256 KB
    float*    Cq = (float*)   (ws + 51 * MB);   // 256 KB
    __bf16*   Xb = (__bf16*)  (ws + 52 * MB);   // 16.02 MB

    k_convW<<<dim3(192),            dim3(256), 0, stream>>>(W, Wt);
    k_convX<<<dim3(4096),           dim3(256), 0, stream>>>(x, Xb);
    k_gemm <<<dim3(768),            dim3(256), 0, stream>>>(Xb, Wt, b, Zb, Fb, Ob);
    k_scan1<<<dim3(BATCH * NCHUNK), dim3(128), 0, stream>>>(Fb, Zb, Aq, Bq);
    k_scan2<<<dim3(BATCH),          dim3(256), 0, stream>>>(Aq, Bq, Cq);
    k_scan3<<<dim3(BATCH * NCHUNK), dim3(128), 0, stream>>>(Fb, Zb, Ob, Cq, out);
}